// Round 3
// baseline (224.485 us; speedup 1.0000x reference)
//
#include <hip/hip_runtime.h>
#include <math.h>

#define NPG  256
#define EPG  4096
#define NG   512
#define FIN  128
#define HD   64
#define TOUT 18
#define KTOP 16
#define SRCL_CAP (EPG + 3*NPG)
#define E_TOT (NG*EPG)

// swizzled h storage: row n, col c  (c-quads stay contiguous; banks spread)
__device__ __forceinline__ int hlidx(int n, int c) {
    return (n << 6) + (c ^ ((n & 7) << 2));
}

__launch_bounds__(512, 4)
__global__ void dgcnn_fused(
    const float* __restrict__ x,
    const int*   __restrict__ ei,
    const float* __restrict__ w0, const float* __restrict__ b0,
    const float* __restrict__ w1, const float* __restrict__ b1,
    const float* __restrict__ w2, const float* __restrict__ b2,
    const float* __restrict__ w3, const float* __restrict__ b3,
    const float* __restrict__ w4, const float* __restrict__ b4,
    const float* __restrict__ c1w, const float* __restrict__ c1b,
    const float* __restrict__ c2w, const float* __restrict__ c2b,
    const float* __restrict__ d1w, const float* __restrict__ d1b,
    const float* __restrict__ d2w, const float* __restrict__ d2b,
    float* __restrict__ out)
{
    __shared__ float s_hl[NPG*64];                  // h / h_lin / final proj rows
    __shared__ unsigned char s_srcl[SRCL_CAP] __attribute__((aligned(4)));
    __shared__ int   s_off[NPG+1];
    __shared__ int   s_cnt[NPG];
    __shared__ float s_invdeg[NPG];
    __shared__ float s_lin5[NPG];
    __shared__ float s_h5[NPG];
    __shared__ int   s_sel[KTOP];
    __shared__ float s_head[592];
    int* s_cur  = (int*)s_head;                     // phase-0 alias (dead before head)
    int* s_outd = (int*)(s_head + 256);             // phase-0 alias

    const int g    = blockIdx.x;
    const int t    = threadIdx.x;
    const int lane = t & 63;
    const int wid  = t >> 6;                        // 0..7
    const int nw   = wid & 3;                       // node-wave 0..3
    const int wg   = wid >> 2;                      // channel half 0/1
    const int n    = nw*64 + lane;                  // owned node
    const int cbase = __builtin_amdgcn_readfirstlane(wg * 32);
    const int obase = __builtin_amdgcn_readfirstlane(wg * 8);
    const int js   = lane >> 4;                     // subgroup id (dst within wave quad)
    const int q4   = (lane & 15) << 2;              // channel quad within row
    const int gbase = g * NPG;
    const int* __restrict__ srcg = ei + (size_t)g * EPG;
    const int* __restrict__ dstg = ei + (size_t)E_TOT + (size_t)g * EPG;

    // ---------------- phase 0: degrees + 4-padded CSR (by dst) ----------------
    if (t < NPG) { s_cnt[t] = 0; s_outd[t] = 0; }
    __syncthreads();
    for (int e = t; e < EPG; e += 512) {
        int s = srcg[e] - gbase, d = dstg[e] - gbase;
        atomicAdd(&s_outd[s], 1);
        atomicAdd(&s_cnt[d], 1);
    }
    __syncthreads();
    if (t < NPG) s_invdeg[t] = 1.0f / (float)(s_outd[t] + 1);
    if (wid == 0) {                                  // wave-parallel prefix of padded counts
        int p4 = lane * 4;
        int c0 = s_cnt[p4], c1 = s_cnt[p4+1], c2 = s_cnt[p4+2], c3 = s_cnt[p4+3];
        int q0 = (c0+3)&~3, q1 = (c1+3)&~3, q2 = (c2+3)&~3, q3 = (c3+3)&~3;
        int tot = q0+q1+q2+q3;
        int run = tot;
        #pragma unroll
        for (int o = 1; o < 64; o <<= 1) {
            int v = __shfl_up(run, o);
            if (lane >= o) run += v;
        }
        int base = run - tot;
        s_off[p4]   = base;
        s_off[p4+1] = base + q0;
        s_off[p4+2] = base + q0 + q1;
        s_off[p4+3] = base + q0 + q1 + q2;
        if (lane == 63) s_off[NPG] = run;
    }
    __syncthreads();
    if (t < NPG) s_cur[t] = s_off[t];
    __syncthreads();
    for (int e = t; e < EPG; e += 512) {
        int s = srcg[e] - gbase, d = dstg[e] - gbase;
        int pos = atomicAdd(&s_cur[d], 1);
        s_srcl[pos] = (unsigned char)s;
    }
    __syncthreads();
    if (t < NPG) {                                   // pad to x4 with sentinel src=t
        int pe = s_off[t+1];
        for (int p = s_cur[t]; p < pe; p++) s_srcl[p] = (unsigned char)t;
    }
    __syncthreads();

    // agg: for all 256 dst, res in regs, then single write-back pass
    auto runAgg = [&]() {
        float4 res[8];
        #pragma unroll
        for (int r = 0; r < 8; r++) {
            int d = r*32 + wid*4 + js;
            int off = s_off[d], pe = s_off[d+1];
            int npad = (pe - off) - s_cnt[d];
            float4 a = *(const float4*)&s_hl[hlidx(d, q4)];
            float cf = (float)(1 - npad);
            a.x *= cf; a.y *= cf; a.z *= cf; a.w *= cf;
            for (int e = off; e < pe; e += 4) {
                unsigned sq = *(const unsigned*)&s_srcl[e];
                #pragma unroll
                for (int m = 0; m < 4; m++) {
                    int src = (sq >> (8*m)) & 255;
                    float4 hv = *(const float4*)&s_hl[hlidx(src, q4)];
                    a.x += hv.x; a.y += hv.y; a.z += hv.z; a.w += hv.w;
                }
            }
            float id = s_invdeg[d];
            res[r].x = tanhf(a.x * id); res[r].y = tanhf(a.y * id);
            res[r].z = tanhf(a.z * id); res[r].w = tanhf(a.w * id);
        }
        __syncthreads();                             // all reads of h_lin complete
        #pragma unroll
        for (int r = 0; r < 8; r++) {
            int d = r*32 + wid*4 + js;
            *(float4*)&s_hl[hlidx(d, q4)] = res[r];
        }
        __syncthreads();
    };

    // ---------------- layer 0: x(global) -> h_lin ----------------
    {
        float acc[32];
        #pragma unroll
        for (int c = 0; c < 32; c++) acc[c] = b0[cbase + c];
        const float* xrow = x + (size_t)(gbase + n) * FIN;
        for (int kq = 0; kq < 32; kq++) {
            float4 hv = *(const float4*)&xrow[kq*4];
            #pragma unroll
            for (int c = 0; c < 32; c++) {
                float4 wq = *(const float4*)&w0[(cbase+c)*FIN + kq*4];
                acc[c] += hv.x*wq.x + hv.y*wq.y + hv.z*wq.z + hv.w*wq.w;
            }
        }
        #pragma unroll
        for (int j = 0; j < 8; j++) {
            float4 v = {acc[4*j], acc[4*j+1], acc[4*j+2], acc[4*j+3]};
            *(float4*)&s_hl[hlidx(n, cbase + 4*j)] = v;
        }
    }
    __syncthreads();
    runAgg();                                        // -> h1 in s_hl

    // ---------------- layers 1..3 + conv1 projection overlap ----------------
    float proj[8];
    #pragma unroll
    for (int o = 0; o < 8; o++) proj[o] = 0.f;

    #pragma unroll 1
    for (int L = 1; L <= 3; L++) {
        const float* w = (L==1) ? w1 : (L==2) ? w2 : w3;
        const float* b = (L==1) ? b1 : (L==2) ? b2 : b3;
        const int loff = (L-1)*64;
        float acc[32];
        #pragma unroll
        for (int c = 0; c < 32; c++) acc[c] = b[cbase + c];
        for (int kq = 0; kq < 16; kq++) {
            float4 hv = *(const float4*)&s_hl[hlidx(n, kq*4)];
            #pragma unroll
            for (int c = 0; c < 32; c++) {
                float4 wq = *(const float4*)&w[(cbase+c)*HD + kq*4];
                acc[c] += hv.x*wq.x + hv.y*wq.y + hv.z*wq.z + hv.w*wq.w;
            }
            #pragma unroll
            for (int o = 0; o < 8; o++) {
                const float* cp = c1w + (obase+o)*257 + loff + kq*4;
                proj[o] += hv.x*cp[0] + hv.y*cp[1] + hv.z*cp[2] + hv.w*cp[3];
            }
        }
        __syncthreads();                             // all reads of h complete
        #pragma unroll
        for (int j = 0; j < 8; j++) {
            float4 v = {acc[4*j], acc[4*j+1], acc[4*j+2], acc[4*j+3]};
            *(float4*)&s_hl[hlidx(n, cbase + 4*j)] = v;
        }
        __syncthreads();
        runAgg();
    }

    // ---------------- layer 4 (64->1) + proj of h4, h5 ----------------
    {
        float lin5 = b4[0];
        for (int kq = 0; kq < 16; kq++) {
            float4 hv = *(const float4*)&s_hl[hlidx(n, kq*4)];
            if (wg == 0) {
                lin5 += hv.x*w4[kq*4] + hv.y*w4[kq*4+1]
                      + hv.z*w4[kq*4+2] + hv.w*w4[kq*4+3];
            }
            #pragma unroll
            for (int o = 0; o < 8; o++) {
                const float* cp = c1w + (obase+o)*257 + 192 + kq*4;
                proj[o] += hv.x*cp[0] + hv.y*cp[1] + hv.z*cp[2] + hv.w*cp[3];
            }
        }
        if (wg == 0) s_lin5[n] = lin5;
        __syncthreads();
        if (t < NPG) {
            int d = t;
            int off = s_off[d], pe = s_off[d+1];
            int npad = (pe - off) - s_cnt[d];
            float a = (float)(1 - npad) * s_lin5[d];
            for (int e = off; e < pe; e += 4) {
                unsigned sq = *(const unsigned*)&s_srcl[e];
                a += s_lin5[sq & 255] + s_lin5[(sq>>8)&255]
                   + s_lin5[(sq>>16)&255] + s_lin5[(sq>>24)&255];
            }
            s_h5[d] = tanhf(a * s_invdeg[d]);
        }
        __syncthreads();
        {
            float h5 = s_h5[n];
            #pragma unroll
            for (int o = 0; o < 8; o++) proj[o] += h5 * c1w[(obase+o)*257 + 256];
        }
        // h4 fully consumed (all kq loops done before earlier barrier) -> store proj rows
        #pragma unroll
        for (int j = 0; j < 2; j++) {
            float4 v = {proj[4*j], proj[4*j+1], proj[4*j+2], proj[4*j+3]};
            *(float4*)&s_hl[hlidx(n, obase + 4*j)] = v;
        }
    }
    __syncthreads();

    // ---------------- top-16 (desc value, asc index ties) ----------------
    if (wid == 0) {
        float v[4]; int idx[4];
        int p4 = lane * 4;
        #pragma unroll
        for (int j = 0; j < 4; j++) { idx[j] = p4 + j; v[j] = s_h5[p4 + j]; }
        for (int r = 0; r < KTOP; r++) {
            float bv = v[0]; int bi = idx[0];
            #pragma unroll
            for (int j = 1; j < 4; j++)
                if (v[j] > bv || (v[j] == bv && idx[j] < bi)) { bv = v[j]; bi = idx[j]; }
            #pragma unroll
            for (int o = 32; o > 0; o >>= 1) {
                float ov = __shfl_xor(bv, o);
                int   oi = __shfl_xor(bi, o);
                if (ov > bv || (ov == bv && oi < bi)) { bv = ov; bi = oi; }
            }
            if ((bi >> 2) == lane) v[bi & 3] = -1e30f;
            if (lane == 0) s_sel[r] = bi;
        }
    }
    __syncthreads();

    // ---------------- head ----------------
    float* s_c1   = s_head;        // [16 o][16 slot]
    float* s_p1   = s_head + 256;  // [16 o][8]
    float* s_flat = s_head + 384;  // 128
    float* s_last = s_head + 512;  // 32
    float* s_outv = s_head + 544;  // 18

    if (t < 256) {
        int sl = t >> 4, o = t & 15;
        int sn = s_sel[sl];
        float vv = s_hl[hlidx(sn, o)] + c1b[o];
        s_c1[o*16 + sl] = fmaxf(vv, 0.f);
    }
    __syncthreads();
    if (t < 128) {
        int o = t >> 3, j = t & 7;
        s_p1[o*8 + j] = fmaxf(s_c1[o*16 + 2*j], s_c1[o*16 + 2*j + 1]);
    }
    __syncthreads();
    if (t < 128) {
        int oc = t >> 2, tt = t & 3;
        float a = c2b[oc];
        #pragma unroll
        for (int ic = 0; ic < 16; ic++)
            #pragma unroll
            for (int kk = 0; kk < 5; kk++)
                a += s_p1[ic*8 + tt + kk] * c2w[(oc*16 + ic)*5 + kk];
        s_flat[oc*4 + tt] = fmaxf(a, 0.f);
    }
    __syncthreads();
    if (t < 32) {
        float a = d1b[t];
        #pragma unroll 16
        for (int i = 0; i < 128; i++) a += s_flat[i] * d1w[t*128 + i];
        a = fmaxf(a, 0.f);
        s_last[t] = a;
        out[2*NG*TOUT + g*32 + t] = a;                 // output 2: last
    }
    __syncthreads();
    if (t < TOUT) {
        float a = d2b[t];
        #pragma unroll
        for (int j = 0; j < 32; j++) a += s_last[j] * d2w[t*32 + j];
        s_outv[t] = a;
        out[NG*TOUT + g*TOUT + t] = a;                 // output 1: logits
    }
    __syncthreads();
    if (t < TOUT) {
        float m = s_outv[0];
        for (int i = 1; i < TOUT; i++) m = fmaxf(m, s_outv[i]);
        float sum = 0.f;
        for (int i = 0; i < TOUT; i++) sum += expf(s_outv[i] - m);
        out[g*TOUT + t] = s_outv[t] - m - logf(sum);   // output 0: log_softmax
    }
}

extern "C" void kernel_launch(void* const* d_in, const int* in_sizes, int n_in,
                              void* d_out, int out_size, void* d_ws, size_t ws_size,
                              hipStream_t stream) {
    (void)in_sizes; (void)n_in; (void)out_size; (void)d_ws; (void)ws_size;
    const float* x   = (const float*)d_in[0];
    const int*   ei  = (const int*)  d_in[1];
    const float* w0  = (const float*)d_in[4];  const float* b0 = (const float*)d_in[5];
    const float* w1  = (const float*)d_in[6];  const float* b1 = (const float*)d_in[7];
    const float* w2  = (const float*)d_in[8];  const float* b2 = (const float*)d_in[9];
    const float* w3  = (const float*)d_in[10]; const float* b3 = (const float*)d_in[11];
    const float* w4  = (const float*)d_in[12]; const float* b4 = (const float*)d_in[13];
    const float* c1w = (const float*)d_in[14]; const float* c1b = (const float*)d_in[15];
    const float* c2w = (const float*)d_in[16]; const float* c2b = (const float*)d_in[17];
    const float* d1w = (const float*)d_in[18]; const float* d1b = (const float*)d_in[19];
    const float* d2w = (const float*)d_in[20]; const float* d2b = (const float*)d_in[21];
    float* out = (float*)d_out;

    dgcnn_fused<<<NG, 512, 0, stream>>>(x, ei,
        w0, b0, w1, b1, w2, b2, w3, b3, w4, b4,
        c1w, c1b, c2w, c2b, d1w, d1b, d2w, d2b, out);
}